// Round 12
// baseline (185.839 us; speedup 1.0000x reference)
//
#include <hip/hip_runtime.h>
#include <hip/hip_bf16.h>

#define DEV static __device__ __forceinline__

typedef __attribute__((ext_vector_type(8))) short short8;
typedef __attribute__((ext_vector_type(4))) short short4v;
typedef __attribute__((ext_vector_type(4))) float float4v;
typedef __attribute__((ext_vector_type(4))) int int4v;

DEV unsigned short f2bf(float f) {
  unsigned int u = __builtin_bit_cast(unsigned int, f);
  u = (u + 0x7fffu + ((u >> 16) & 1u)) >> 16;
  return (unsigned short)u;
}

DEV __attribute__((address_space(3))) void* to_lds(void* p) {
  return (__attribute__((address_space(3))) void*)p;
}
DEV const __attribute__((address_space(1))) void* to_glb(const void* p) {
  return (const __attribute__((address_space(1))) void*)p;
}

DEV float4v zero4() { float4v z = {0.f, 0.f, 0.f, 0.f}; return z; }

DEV float ex2(float x) {
  float r;
  asm("v_exp_f32 %0, %1" : "=v"(r) : "v"(x));
  return r;
}
DEV unsigned int cvtpk(float lo, float hi) {
  unsigned int r;
  asm("v_cvt_pk_bf16_f32 %0, %1, %2" : "=v"(r) : "v"(lo), "v"(hi));
  return r;
}

// ---------------------------------------------------------------- merged convert
__global__ __launch_bounds__(256)
void cvt3_kn(const float* __restrict__ x, const float* __restrict__ wq,
             const float* __restrict__ wp, unsigned short* __restrict__ xb,
             unsigned short* __restrict__ wqb, unsigned short* __restrict__ wpb) {
  const int NX = 8192 * 1024, NQ = 3072 * 1024, NP = 1024 * 1024;
  const int total = (NX + NQ + NP) / 4;
  int u = blockIdx.x * blockDim.x + threadIdx.x;
  int stride = gridDim.x * blockDim.x;
  for (; u < total; u += stride) {
    int i = u * 4;
    const float* s;
    unsigned short* d;
    if (i < NX) {
      s = x + i; d = xb + i;
    } else if (i < NX + NQ) {
      s = wq + (i - NX); d = wqb + (i - NX);
    } else {
      s = wp + (i - NX - NQ); d = wpb + (i - NX - NQ);
    }
    float4v v = *reinterpret_cast<const float4v*>(s);
    short4v o;
    o[0] = (short)f2bf(v[0]);
    o[1] = (short)f2bf(v[1]);
    o[2] = (short)f2bf(v[2]);
    o[3] = (short)f2bf(v[3]);
    *reinterpret_cast<short4v*>(d) = o;
  }
}

// ---------------------------------------------------------------- GEMM (R6-exact)
// 128x128 tile, BK=64, 4 waves, m97 structure (proven 61.5us/838TF on QKV;
// big-tile 1-block/CU variants all regressed: R8/R9/R10). XCD-chunked swizzle.
template<int EPI>
DEV void gemm_bt_body(const unsigned short* __restrict__ A, const unsigned short* __restrict__ B,
                      const float* __restrict__ bias, void* __restrict__ Cout,
                      unsigned short* __restrict__ vtout, int M, int N, int K,
                      unsigned short* sA, unsigned short* sB) {
  const int t = threadIdx.x;
  const int wave = t >> 6, lane = t & 63;
  const int wm = wave >> 1, wn = wave & 1;
  const int nwg = gridDim.x * gridDim.y;
  const int lid = blockIdx.y * gridDim.x + blockIdx.x;
  const int swz = (lid & 7) * (nwg >> 3) + (lid >> 3);  // nwg % 8 == 0
  const int m0 = (swz / gridDim.x) * 128, n0 = (swz % gridDim.x) * 128;
  const int l15 = lane & 15, l4 = lane >> 4;

  float4v acc[4][4];
#pragma unroll
  for (int i = 0; i < 4; i++)
#pragma unroll
    for (int j = 0; j < 4; j++) acc[i][j] = zero4();

  const int row_s = t >> 3;
  const int cols_s = ((t & 7) ^ ((t >> 3) & 7)) * 8;

  for (int k0 = 0; k0 < K; k0 += 64) {
    __syncthreads();
#pragma unroll
    for (int i = 0; i < 4; i++) {
      const unsigned short* ga = &A[(size_t)(m0 + row_s + i * 32) * K + k0 + cols_s];
      __builtin_amdgcn_global_load_lds(to_glb(ga), to_lds(&sA[(i * 4096 + wave * 1024) / 2]), 16, 0, 0);
    }
#pragma unroll
    for (int i = 0; i < 4; i++) {
      const unsigned short* gb = &B[(size_t)(n0 + row_s + i * 32) * K + k0 + cols_s];
      __builtin_amdgcn_global_load_lds(to_glb(gb), to_lds(&sB[(i * 4096 + wave * 1024) / 2]), 16, 0, 0);
    }
    __syncthreads();
#pragma unroll
    for (int kc = 0; kc < 2; kc++) {
      short8 af[4], bf[4];
#pragma unroll
      for (int mf = 0; mf < 4; mf++) {
        int off = ((wm * 64 + mf * 16 + l15) * 128 + kc * 64 + l4 * 16) ^ ((l15 & 7) << 4);
        af[mf] = *reinterpret_cast<const short8*>((const char*)sA + off);
      }
#pragma unroll
      for (int nf = 0; nf < 4; nf++) {
        int off = ((wn * 64 + nf * 16 + l15) * 128 + kc * 64 + l4 * 16) ^ ((l15 & 7) << 4);
        bf[nf] = *reinterpret_cast<const short8*>((const char*)sB + off);
      }
      __builtin_amdgcn_s_setprio(1);
#pragma unroll
      for (int mf = 0; mf < 4; mf++)
#pragma unroll
        for (int nf = 0; nf < 4; nf++)
          acc[mf][nf] = __builtin_amdgcn_mfma_f32_16x16x32_bf16(af[mf], bf[nf], acc[mf][nf], 0, 0, 0);
      __builtin_amdgcn_s_setprio(0);
    }
  }

#pragma unroll
  for (int mf = 0; mf < 4; mf++) {
    const int row0 = m0 + wm * 64 + mf * 16 + l4 * 4;
#pragma unroll
    for (int nf = 0; nf < 4; nf++) {
      const int col = n0 + wn * 64 + nf * 16 + l15;
      float vv[4];
#pragma unroll
      for (int r = 0; r < 4; r++) vv[r] = acc[mf][nf][r] + bias[col];
      if (EPI == 1) {
#pragma unroll
        for (int r = 0; r < 4; r++)
          ((float*)Cout)[(size_t)(row0 + r) * N + col] = vv[r];
      } else {
        if (col < 2048) {
          const float s = (col < 1024) ? 0.18033688f : 1.0f;  // 0.125*log2(e) on q
#pragma unroll
          for (int r = 0; r < 4; r++)
            ((unsigned short*)Cout)[(size_t)(row0 + r) * 2048 + col] = f2bf(vv[r] * s);
        } else {
          const int hv = col - 2048;
          const int R = ((row0 >> 11) * 16 + (hv >> 6)) * 64 + (hv & 63);
          const int tc = row0 & 2047;
          unsigned long long w = (unsigned long long)cvtpk(vv[0], vv[1]) |
                                 ((unsigned long long)cvtpk(vv[2], vv[3]) << 32);
          *(unsigned long long*)&vtout[(size_t)R * 2048 + tc] = w;
        }
      }
    }
  }
}

__global__ __launch_bounds__(256, 2)
void gemm_qkv_kn(const unsigned short* __restrict__ A, const unsigned short* __restrict__ B,
                 const float* __restrict__ bias, unsigned short* __restrict__ qkout,
                 unsigned short* __restrict__ vtout, int M, int N, int K) {
  __shared__ unsigned short sA[128 * 64];
  __shared__ unsigned short sB[128 * 64];
  gemm_bt_body<2>(A, B, bias, qkout, vtout, M, N, K, sA, sB);
}

__global__ __launch_bounds__(256, 2)
void gemm_proj_kn(const unsigned short* __restrict__ A, const unsigned short* __restrict__ B,
                  const float* __restrict__ bias, float* __restrict__ Cout,
                  int M, int N, int K) {
  __shared__ unsigned short sA[128 * 64];
  __shared__ unsigned short sB[128 * 64];
  gemm_bt_body<1>(A, B, bias, Cout, nullptr, M, N, K, sA, sB);
}

// ---------------------------------------------------------------- attention
// 256-q blocks (4 waves x 64 q): halves (q,kv) tile count vs 128-q -> halves
// K/V LDS re-read traffic; each wave-tile: 8KB K + 8KB V feed 72 MFMA.
// Static softmax in log2 units (Q pre-scaled in GEMM); l via ones-MFMA.
// Grid (64 bh, 8 y), qt = y<4 ? y : 11-y (CU's two rounds sum to equal work);
// 8 q-blocks of a head land on one XCD (ids differ by 64 = 0 mod 8).
// LDS 64KB -> 2 blocks/CU.
__global__ __launch_bounds__(256, 2)
void attn_kn(const unsigned short* __restrict__ qk, const unsigned short* __restrict__ vt,
             unsigned short* __restrict__ y) {
  __shared__ unsigned short sK[2][4096];  // [64 kv][64 d], key (kv&7)<<4
  __shared__ unsigned short sV[2][4096];  // [64 d][64 kv], key (d&7)<<4
  __shared__ unsigned short sP[4][4096];  // per-wave [64 q][64 kv], key (q&7)<<4
  const int t = threadIdx.x;
  const int wave = t >> 6, lane = t & 63;
  const int l15 = lane & 15, l4 = lane >> 4;
  const int bh = blockIdx.x, b = bh >> 4, h = bh & 15;
  const int yb_ = blockIdx.y;
  const int qt = (yb_ < 4) ? yb_ : 11 - yb_;  // pair (y, y+4) sums to 7
  const int q0w = qt * 256 + wave * 64;
  const size_t base = (size_t)b * 2048 * 2048;
  const unsigned short* Qp = qk + base + h * 64;
  const unsigned short* Kp = Qp + 1024;
  const unsigned short* Vt = vt + (size_t)bh * 64 * 2048;
  unsigned short* yb = y + (size_t)b * 2048 * 1024 + h * 64;

  short8 ones8;
#pragma unroll
  for (int j = 0; j < 8; j++) ones8[j] = (short)0x3F80;

  short8 qf[4][2];
#pragma unroll
  for (int m = 0; m < 4; m++)
#pragma unroll
    for (int kc = 0; kc < 2; kc++)
      qf[m][kc] = *reinterpret_cast<const short8*>(
          &Qp[(size_t)(q0w + m * 16 + l15) * 2048 + kc * 32 + l4 * 8]);

  float4v o_acc[4][4];
#pragma unroll
  for (int m = 0; m < 4; m++)
#pragma unroll
    for (int f = 0; f < 4; f++) o_acc[m][f] = zero4();
  float4v acc_l[4] = {zero4(), zero4(), zero4(), zero4()};

  auto stage_k = [&](int kv0, int bi) {
#pragma unroll
    for (int i = 0; i < 2; i++) {
      int unit = t + i * 256;
      int row = unit >> 3, sl = unit & 7;
      const unsigned short* g = Kp + (size_t)(kv0 + row) * 2048 + (sl ^ (row & 7)) * 8;
      __builtin_amdgcn_global_load_lds(to_glb(g), to_lds(&sK[bi][unit * 8]), 16, 0, 0);
    }
  };
  auto stage_v = [&](int kv0, int bi) {
#pragma unroll
    for (int i = 0; i < 2; i++) {
      int unit = t + i * 256;
      int d = unit >> 3, sl = unit & 7;
      const unsigned short* g = Vt + (size_t)d * 2048 + kv0 + (sl ^ (d & 7)) * 8;
      __builtin_amdgcn_global_load_lds(to_glb(g), to_lds(&sV[bi][unit * 8]), 16, 0, 0);
    }
  };

  const int nt = (qt + 1) * 4;  // kv tiles of 64 covering (qt+1)*256 rows
  stage_k(0, 0);
  stage_v(0, 0);
  __syncthreads();

  for (int ti = 0; ti < nt; ti++) {
    const int cur = ti & 1;
    const int kv0 = ti * 64;
    const bool last = (ti + 1 == nt);
    if (!last) { stage_k(kv0 + 64, cur ^ 1); stage_v(kv0 + 64, cur ^ 1); }

    if (kv0 <= q0w + 63) {
      const char* Kb = (const char*)sK[cur];
      const char* Vb = (const char*)sV[cur];
      char* Pb = (char*)sP[wave];

      // S^T = K . Q^T : rows kv (c*16+l4*4+r), cols q (l15); log2 units
      float4v st[4][4];  // [m][c]
#pragma unroll
      for (int m = 0; m < 4; m++)
#pragma unroll
        for (int c = 0; c < 4; c++) st[m][c] = zero4();
#pragma unroll
      for (int kc = 0; kc < 2; kc++) {
        short8 ka[4];
#pragma unroll
        for (int c = 0; c < 4; c++) {
          int off = ((c * 16 + l15) * 128 + kc * 64 + l4 * 16) ^ ((l15 & 7) << 4);
          ka[c] = *reinterpret_cast<const short8*>(Kb + off);
        }
        __builtin_amdgcn_s_setprio(1);
#pragma unroll
        for (int c = 0; c < 4; c++)
#pragma unroll
          for (int m = 0; m < 4; m++)
            st[m][c] = __builtin_amdgcn_mfma_f32_16x16x32_bf16(ka[c], qf[m][kc], st[m][c], 0, 0, 0);
        __builtin_amdgcn_s_setprio(0);
      }

      // causal mask on diagonal tiles, then P = exp2(s) (static softmax)
#pragma unroll
      for (int m = 0; m < 4; m++) {
        if (kv0 + 63 > q0w + m * 16) {
          const int qrow = q0w + m * 16 + l15;
#pragma unroll
          for (int c = 0; c < 4; c++)
#pragma unroll
            for (int r = 0; r < 4; r++) {
              int kv = kv0 + c * 16 + l4 * 4 + r;
              if (kv > qrow) st[m][c][r] = -1e30f;
            }
        }
#pragma unroll
        for (int c = 0; c < 4; c++) {
          float p0 = ex2(st[m][c][0]), p1 = ex2(st[m][c][1]);
          float p2 = ex2(st[m][c][2]), p3 = ex2(st[m][c][3]);
          unsigned long long w = (unsigned long long)cvtpk(p0, p1) |
                                 ((unsigned long long)cvtpk(p2, p3) << 32);
          int off = ((m * 16 + l15) * 128 + (c * 16 + l4 * 4) * 2) ^ ((l15 & 7) << 4);
          *(unsigned long long*)(Pb + off) = w;
        }
      }
      asm volatile("s_waitcnt lgkmcnt(0)" ::: "memory");
      __builtin_amdgcn_sched_barrier(0);

      // PV: O[q][d] += P[q][k] * V^T[d][k]; l[q] += P[q][k] * 1
#pragma unroll
      for (int kc = 0; kc < 2; kc++) {
        short8 pa[4];
#pragma unroll
        for (int m = 0; m < 4; m++) {
          int off = ((m * 16 + l15) * 128 + kc * 64 + l4 * 16) ^ ((l15 & 7) << 4);
          pa[m] = *reinterpret_cast<const short8*>(Pb + off);
        }
        short8 vbf[4];
#pragma unroll
        for (int f = 0; f < 4; f++) {
          int d = f * 16 + l15;
          int off = (d * 128 + kc * 64 + l4 * 16) ^ ((d & 7) << 4);
          vbf[f] = *reinterpret_cast<const short8*>(Vb + off);
        }
        __builtin_amdgcn_s_setprio(1);
#pragma unroll
        for (int f = 0; f < 4; f++)
#pragma unroll
          for (int m = 0; m < 4; m++)
            o_acc[m][f] = __builtin_amdgcn_mfma_f32_16x16x32_bf16(pa[m], vbf[f], o_acc[m][f], 0, 0, 0);
#pragma unroll
        for (int m = 0; m < 4; m++)
          acc_l[m] = __builtin_amdgcn_mfma_f32_16x16x32_bf16(pa[m], ones8, acc_l[m], 0, 0, 0);
        __builtin_amdgcn_s_setprio(0);
      }
    }
    __syncthreads();
  }

#pragma unroll
  for (int m = 0; m < 4; m++) {
    float lr[4];
#pragma unroll
    for (int r = 0; r < 4; r++) lr[r] = 1.0f / acc_l[m][r];
#pragma unroll
    for (int f = 0; f < 4; f++)
#pragma unroll
      for (int r = 0; r < 4; r++) {
        int q = q0w + m * 16 + l4 * 4 + r;
        yb[(size_t)q * 1024 + f * 16 + l15] = f2bf(o_acc[m][f][r] * lr[r]);
      }
  }
}

// ---------------------------------------------------------------- launch
extern "C" void kernel_launch(void* const* d_in, const int* in_sizes, int n_in,
                              void* d_out, int out_size, void* d_ws, size_t ws_size,
                              hipStream_t stream) {
  const float* x = (const float*)d_in[0];
  const float* w_qkv = (const float*)d_in[1];
  const float* b_qkv = (const float*)d_in[2];
  const float* w_proj = (const float*)d_in[3];
  const float* b_proj = (const float*)d_in[4];
  float* out = (float*)d_out;
  char* ws = (char*)d_ws;

  const int M = 4 * 2048;
  unsigned short* x_bf = (unsigned short*)ws;                        // 16 MB
  unsigned short* wqkv_bf = (unsigned short*)(ws + (22ull << 20));   // 6 MB
  unsigned short* wproj_bf = (unsigned short*)(ws + (28ull << 20));  // 2 MB
  unsigned short* qk_buf = (unsigned short*)(ws + (30ull << 20));    // 32 MB [8192][2048]
  unsigned short* vt = (unsigned short*)(ws + (62ull << 20));        // 16 MB [4096][2048]
  unsigned short* y_bf = x_bf;  // reuse x region after QKV GEMM

  cvt3_kn<<<2048, 256, 0, stream>>>(x, w_qkv, w_proj, x_bf, wqkv_bf, wproj_bf);

  gemm_qkv_kn<<<dim3(24, 64), 256, 0, stream>>>(
      x_bf, wqkv_bf, b_qkv, qk_buf, vt, M, 3072, 1024);

  attn_kn<<<dim3(64, 8), 256, 0, stream>>>(qk_buf, vt, y_bf);

  gemm_proj_kn<<<dim3(8, 64), 256, 0, stream>>>(
      y_bf, wproj_bf, b_proj, out, M, 1024, 1024);
}

// Round 13
// 147.121 us; speedup vs baseline: 1.2632x; 1.2632x over previous
//
#include <hip/hip_runtime.h>
#include <hip/hip_bf16.h>

#define DEV static __device__ __forceinline__

typedef __attribute__((ext_vector_type(8))) short short8;
typedef __attribute__((ext_vector_type(4))) short short4v;
typedef __attribute__((ext_vector_type(4))) float float4v;
typedef __attribute__((ext_vector_type(4))) int int4v;

DEV unsigned short f2bf(float f) {
  unsigned int u = __builtin_bit_cast(unsigned int, f);
  u = (u + 0x7fffu + ((u >> 16) & 1u)) >> 16;
  return (unsigned short)u;
}

DEV __attribute__((address_space(3))) void* to_lds(void* p) {
  return (__attribute__((address_space(3))) void*)p;
}
DEV const __attribute__((address_space(1))) void* to_glb(const void* p) {
  return (const __attribute__((address_space(1))) void*)p;
}

DEV float4v zero4() { float4v z = {0.f, 0.f, 0.f, 0.f}; return z; }

DEV float ex2(float x) {
  float r;
  asm("v_exp_f32 %0, %1" : "=v"(r) : "v"(x));
  return r;
}
DEV unsigned int cvtpk(float lo, float hi) {
  unsigned int r;
  asm("v_cvt_pk_bf16_f32 %0, %1, %2" : "=v"(r) : "v"(lo), "v"(hi));
  return r;
}

// ---------------------------------------------------------------- merged convert
__global__ __launch_bounds__(256)
void cvt3_kn(const float* __restrict__ x, const float* __restrict__ wq,
             const float* __restrict__ wp, unsigned short* __restrict__ xb,
             unsigned short* __restrict__ wqb, unsigned short* __restrict__ wpb) {
  const int NX = 8192 * 1024, NQ = 3072 * 1024, NP = 1024 * 1024;
  const int total = (NX + NQ + NP) / 4;
  int u = blockIdx.x * blockDim.x + threadIdx.x;
  int stride = gridDim.x * blockDim.x;
  for (; u < total; u += stride) {
    int i = u * 4;
    const float* s;
    unsigned short* d;
    if (i < NX) {
      s = x + i; d = xb + i;
    } else if (i < NX + NQ) {
      s = wq + (i - NX); d = wqb + (i - NX);
    } else {
      s = wp + (i - NX - NQ); d = wpb + (i - NX - NQ);
    }
    float4v v = *reinterpret_cast<const float4v*>(s);
    short4v o;
    o[0] = (short)f2bf(v[0]);
    o[1] = (short)f2bf(v[1]);
    o[2] = (short)f2bf(v[2]);
    o[3] = (short)f2bf(v[3]);
    *reinterpret_cast<short4v*>(d) = o;
  }
}

// ---------------------------------------------------------------- QKV GEMM
// 128x192 tile, BK=64, 4 waves (2x2) of 64x96 wave-tiles: 25% fewer LDS-read
// instrs + 25% fewer LDS bytes staged per output area than the 128x128 m97
// config, SAME single-buffer 2-barrier skeleton (the only structure that has
// survived: R8/R9/R10 restructures all regressed). XCD-chunked swizzle.
// Split epilogue: q scaled by 0.125*log2e, k plain, v -> vt[(b*16+h)*64+d][t].
__global__ __launch_bounds__(256, 2)
void gemm_qkv_kn(const unsigned short* __restrict__ A, const unsigned short* __restrict__ B,
                 const float* __restrict__ bias, unsigned short* __restrict__ qkout,
                 unsigned short* __restrict__ vtout, int M, int N, int K) {
  __shared__ unsigned short sA[128 * 64];
  __shared__ unsigned short sB[192 * 64];
  const int t = threadIdx.x;
  const int wave = t >> 6, lane = t & 63;
  const int wm = wave >> 1, wn = wave & 1;
  const int nwg = gridDim.x * gridDim.y;
  const int lid = blockIdx.y * gridDim.x + blockIdx.x;
  const int swz = (lid & 7) * (nwg >> 3) + (lid >> 3);  // nwg % 8 == 0
  const int m0 = (swz / gridDim.x) * 128, n0 = (swz % gridDim.x) * 192;
  const int l15 = lane & 15, l4 = lane >> 4;
  const int lkey = (l15 & 7) << 4;

  float4v acc[4][6];
#pragma unroll
  for (int i = 0; i < 4; i++)
#pragma unroll
    for (int j = 0; j < 6; j++) acc[i][j] = zero4();

  for (int k0 = 0; k0 < K; k0 += 64) {
    __syncthreads();
#pragma unroll
    for (int p = 0; p < 4; p++) {  // A: 128 rows
      int unit = t + p * 256, row = unit >> 3, sl = unit & 7;
      const unsigned short* g = &A[(size_t)(m0 + row) * K + k0 + (sl ^ (row & 7)) * 8];
      __builtin_amdgcn_global_load_lds(to_glb(g), to_lds(&sA[unit * 8]), 16, 0, 0);
    }
#pragma unroll
    for (int p = 0; p < 6; p++) {  // B: 192 rows
      int unit = t + p * 256, row = unit >> 3, sl = unit & 7;
      const unsigned short* g = &B[(size_t)(n0 + row) * K + k0 + (sl ^ (row & 7)) * 8];
      __builtin_amdgcn_global_load_lds(to_glb(g), to_lds(&sB[unit * 8]), 16, 0, 0);
    }
    __syncthreads();
#pragma unroll
    for (int kc = 0; kc < 2; kc++) {
      short8 af[4], bf[6];
#pragma unroll
      for (int mf = 0; mf < 4; mf++) {
        int off = ((wm * 64 + mf * 16 + l15) * 128 + kc * 64 + l4 * 16) ^ lkey;
        af[mf] = *reinterpret_cast<const short8*>((const char*)sA + off);
      }
#pragma unroll
      for (int nf = 0; nf < 6; nf++) {
        int off = ((wn * 96 + nf * 16 + l15) * 128 + kc * 64 + l4 * 16) ^ lkey;
        bf[nf] = *reinterpret_cast<const short8*>((const char*)sB + off);
      }
      __builtin_amdgcn_s_setprio(1);
#pragma unroll
      for (int mf = 0; mf < 4; mf++)
#pragma unroll
        for (int nf = 0; nf < 6; nf++)
          acc[mf][nf] = __builtin_amdgcn_mfma_f32_16x16x32_bf16(af[mf], bf[nf], acc[mf][nf], 0, 0, 0);
      __builtin_amdgcn_s_setprio(0);
    }
  }

#pragma unroll
  for (int mf = 0; mf < 4; mf++) {
    const int row0 = m0 + wm * 64 + mf * 16 + l4 * 4;
#pragma unroll
    for (int nf = 0; nf < 6; nf++) {
      const int col = n0 + wn * 96 + nf * 16 + l15;
      float vv[4];
#pragma unroll
      for (int r = 0; r < 4; r++) vv[r] = acc[mf][nf][r] + bias[col];
      if (col < 2048) {
        const float s = (col < 1024) ? 0.18033688f : 1.0f;  // 0.125*log2(e) on q
#pragma unroll
        for (int r = 0; r < 4; r++)
          qkout[(size_t)(row0 + r) * 2048 + col] = f2bf(vv[r] * s);
      } else {
        const int hv = col - 2048;
        const int R = ((row0 >> 11) * 16 + (hv >> 6)) * 64 + (hv & 63);
        const int tc = row0 & 2047;
        unsigned long long w = (unsigned long long)cvtpk(vv[0], vv[1]) |
                               ((unsigned long long)cvtpk(vv[2], vv[3]) << 32);
        *(unsigned long long*)&vtout[(size_t)R * 2048 + tc] = w;
      }
    }
  }
}

// ---------------------------------------------------------------- proj GEMM (R6-exact)
__global__ __launch_bounds__(256, 2)
void gemm_proj_kn(const unsigned short* __restrict__ A, const unsigned short* __restrict__ B,
                  const float* __restrict__ bias, float* __restrict__ Cout,
                  int M, int N, int K) {
  __shared__ unsigned short sA[128 * 64];
  __shared__ unsigned short sB[128 * 64];
  const int t = threadIdx.x;
  const int wave = t >> 6, lane = t & 63;
  const int wm = wave >> 1, wn = wave & 1;
  const int nwg = gridDim.x * gridDim.y;
  const int lid = blockIdx.y * gridDim.x + blockIdx.x;
  const int swz = (lid & 7) * (nwg >> 3) + (lid >> 3);
  const int m0 = (swz / gridDim.x) * 128, n0 = (swz % gridDim.x) * 128;
  const int l15 = lane & 15, l4 = lane >> 4;

  float4v acc[4][4];
#pragma unroll
  for (int i = 0; i < 4; i++)
#pragma unroll
    for (int j = 0; j < 4; j++) acc[i][j] = zero4();

  const int row_s = t >> 3;
  const int cols_s = ((t & 7) ^ ((t >> 3) & 7)) * 8;

  for (int k0 = 0; k0 < K; k0 += 64) {
    __syncthreads();
#pragma unroll
    for (int i = 0; i < 4; i++) {
      const unsigned short* ga = &A[(size_t)(m0 + row_s + i * 32) * K + k0 + cols_s];
      __builtin_amdgcn_global_load_lds(to_glb(ga), to_lds(&sA[(i * 4096 + wave * 1024) / 2]), 16, 0, 0);
    }
#pragma unroll
    for (int i = 0; i < 4; i++) {
      const unsigned short* gb = &B[(size_t)(n0 + row_s + i * 32) * K + k0 + cols_s];
      __builtin_amdgcn_global_load_lds(to_glb(gb), to_lds(&sB[(i * 4096 + wave * 1024) / 2]), 16, 0, 0);
    }
    __syncthreads();
#pragma unroll
    for (int kc = 0; kc < 2; kc++) {
      short8 af[4], bf[4];
#pragma unroll
      for (int mf = 0; mf < 4; mf++) {
        int off = ((wm * 64 + mf * 16 + l15) * 128 + kc * 64 + l4 * 16) ^ ((l15 & 7) << 4);
        af[mf] = *reinterpret_cast<const short8*>((const char*)sA + off);
      }
#pragma unroll
      for (int nf = 0; nf < 4; nf++) {
        int off = ((wn * 64 + nf * 16 + l15) * 128 + kc * 64 + l4 * 16) ^ ((l15 & 7) << 4);
        bf[nf] = *reinterpret_cast<const short8*>((const char*)sB + off);
      }
      __builtin_amdgcn_s_setprio(1);
#pragma unroll
      for (int mf = 0; mf < 4; mf++)
#pragma unroll
        for (int nf = 0; nf < 4; nf++)
          acc[mf][nf] = __builtin_amdgcn_mfma_f32_16x16x32_bf16(af[mf], bf[nf], acc[mf][nf], 0, 0, 0);
      __builtin_amdgcn_s_setprio(0);
    }
  }

#pragma unroll
  for (int mf = 0; mf < 4; mf++) {
    const int row0 = m0 + wm * 64 + mf * 16 + l4 * 4;
#pragma unroll
    for (int nf = 0; nf < 4; nf++) {
      const int col = n0 + wn * 64 + nf * 16 + l15;
#pragma unroll
      for (int r = 0; r < 4; r++)
        Cout[(size_t)(row0 + r) * N + col] = acc[mf][nf][r] + bias[col];
    }
  }
}

// ---------------------------------------------------------------- attention (R11-exact)
// 128-q blocks (4 waves x 32 q), static softmax in log2 units (Q pre-scaled
// in GEMM), K and V^T staged via linear global_load_lds, l via ones-MFMA,
// balanced qt permutation. Proven ~58us; the 256-q variant regressed (R12:
// solo-tail at 4 waves/CU).
__global__ __launch_bounds__(256, 3)
void attn_kn(const unsigned short* __restrict__ qk, const unsigned short* __restrict__ vt,
             unsigned short* __restrict__ y) {
  __shared__ unsigned short sK[2][4096];  // [64 kv][64 d], key (kv&7)<<4
  __shared__ unsigned short sV[2][4096];  // [64 d][64 kv], key (d&7)<<4
  __shared__ unsigned short sP[4][2048];  // per-wave [32 q][64 kv], key (q&7)<<4
  const int t = threadIdx.x;
  const int wave = t >> 6, lane = t & 63;
  const int l15 = lane & 15, l4 = lane >> 4;
  const int bh = blockIdx.x, b = bh >> 4, h = bh & 15;
  const int yb_ = blockIdx.y;
  const int qt = ((yb_ >> 2) & 1) ? ((yb_ < 8) ? yb_ + 4 : yb_ - 12) : 15 - yb_;
  const int q0w = qt * 128 + wave * 32;
  const size_t base = (size_t)b * 2048 * 2048;
  const unsigned short* Qp = qk + base + h * 64;
  const unsigned short* Kp = Qp + 1024;
  const unsigned short* Vt = vt + (size_t)bh * 64 * 2048;
  unsigned short* yb = y + (size_t)b * 2048 * 1024 + h * 64;

  short8 ones8;
#pragma unroll
  for (int j = 0; j < 8; j++) ones8[j] = (short)0x3F80;

  short8 qf[2][2];
#pragma unroll
  for (int m = 0; m < 2; m++)
#pragma unroll
    for (int kc = 0; kc < 2; kc++)
      qf[m][kc] = *reinterpret_cast<const short8*>(
          &Qp[(size_t)(q0w + m * 16 + l15) * 2048 + kc * 32 + l4 * 8]);

  float4v o_acc[2][4];
#pragma unroll
  for (int m = 0; m < 2; m++)
#pragma unroll
    for (int f = 0; f < 4; f++) o_acc[m][f] = zero4();
  float4v acc_l[2] = {zero4(), zero4()};

  auto stage_k = [&](int kv0, int bi) {
#pragma unroll
    for (int i = 0; i < 2; i++) {
      int unit = t + i * 256;
      int row = unit >> 3, sl = unit & 7;
      const unsigned short* g = Kp + (size_t)(kv0 + row) * 2048 + (sl ^ (row & 7)) * 8;
      __builtin_amdgcn_global_load_lds(to_glb(g), to_lds(&sK[bi][unit * 8]), 16, 0, 0);
    }
  };
  auto stage_v = [&](int kv0, int bi) {
#pragma unroll
    for (int i = 0; i < 2; i++) {
      int unit = t + i * 256;
      int d = unit >> 3, sl = unit & 7;
      const unsigned short* g = Vt + (size_t)d * 2048 + kv0 + (sl ^ (d & 7)) * 8;
      __builtin_amdgcn_global_load_lds(to_glb(g), to_lds(&sV[bi][unit * 8]), 16, 0, 0);
    }
  };

  const int nt = 2 * qt + 2;
  stage_k(0, 0);
  stage_v(0, 0);
  __syncthreads();

  for (int ti = 0; ti < nt; ti++) {
    const int cur = ti & 1;
    const int kv0 = ti * 64;
    const bool last = (ti + 1 == nt);
    if (!last) { stage_k(kv0 + 64, cur ^ 1); stage_v(kv0 + 64, cur ^ 1); }

    if (kv0 <= q0w + 31) {
      const char* Kb = (const char*)sK[cur];
      const char* Vb = (const char*)sV[cur];
      char* Pb = (char*)sP[wave];

      float4v st[2][4];
#pragma unroll
      for (int m = 0; m < 2; m++)
#pragma unroll
        for (int c = 0; c < 4; c++) st[m][c] = zero4();
#pragma unroll
      for (int kc = 0; kc < 2; kc++) {
        short8 ka[4];
#pragma unroll
        for (int c = 0; c < 4; c++) {
          int off = ((c * 16 + l15) * 128 + kc * 64 + l4 * 16) ^ ((l15 & 7) << 4);
          ka[c] = *reinterpret_cast<const short8*>(Kb + off);
        }
        __builtin_amdgcn_s_setprio(1);
#pragma unroll
        for (int c = 0; c < 4; c++) {
          st[0][c] = __builtin_amdgcn_mfma_f32_16x16x32_bf16(ka[c], qf[0][kc], st[0][c], 0, 0, 0);
          st[1][c] = __builtin_amdgcn_mfma_f32_16x16x32_bf16(ka[c], qf[1][kc], st[1][c], 0, 0, 0);
        }
        __builtin_amdgcn_s_setprio(0);
      }

#pragma unroll
      for (int m = 0; m < 2; m++) {
        if (kv0 + 63 > q0w + m * 16) {
          const int qrow = q0w + m * 16 + l15;
#pragma unroll
          for (int c = 0; c < 4; c++)
#pragma unroll
            for (int r = 0; r < 4; r++) {
              int kv = kv0 + c * 16 + l4 * 4 + r;
              if (kv > qrow) st[m][c][r] = -1e30f;
            }
        }
#pragma unroll
        for (int c = 0; c < 4; c++) {
          float p0 = ex2(st[m][c][0]), p1 = ex2(st[m][c][1]);
          float p2 = ex2(st[m][c][2]), p3 = ex2(st[m][c][3]);
          unsigned long long w = (unsigned long long)cvtpk(p0, p1) |
                                 ((unsigned long long)cvtpk(p2, p3) << 32);
          int off = ((m * 16 + l15) * 128 + (c * 16 + l4 * 4) * 2) ^ ((l15 & 7) << 4);
          *(unsigned long long*)(Pb + off) = w;
        }
      }
      asm volatile("s_waitcnt lgkmcnt(0)" ::: "memory");
      __builtin_amdgcn_sched_barrier(0);

#pragma unroll
      for (int kc = 0; kc < 2; kc++) {
        short8 pa[2];
#pragma unroll
        for (int m = 0; m < 2; m++) {
          int off = ((m * 16 + l15) * 128 + kc * 64 + l4 * 16) ^ ((l15 & 7) << 4);
          pa[m] = *reinterpret_cast<const short8*>(Pb + off);
        }
        short8 vbf[4];
#pragma unroll
        for (int f = 0; f < 4; f++) {
          int d = f * 16 + l15;
          int off = (d * 128 + kc * 64 + l4 * 16) ^ ((d & 7) << 4);
          vbf[f] = *reinterpret_cast<const short8*>(Vb + off);
        }
        __builtin_amdgcn_s_setprio(1);
#pragma unroll
        for (int f = 0; f < 4; f++) {
          o_acc[0][f] = __builtin_amdgcn_mfma_f32_16x16x32_bf16(pa[0], vbf[f], o_acc[0][f], 0, 0, 0);
          o_acc[1][f] = __builtin_amdgcn_mfma_f32_16x16x32_bf16(pa[1], vbf[f], o_acc[1][f], 0, 0, 0);
        }
        acc_l[0] = __builtin_amdgcn_mfma_f32_16x16x32_bf16(pa[0], ones8, acc_l[0], 0, 0, 0);
        acc_l[1] = __builtin_amdgcn_mfma_f32_16x16x32_bf16(pa[1], ones8, acc_l[1], 0, 0, 0);
        __builtin_amdgcn_s_setprio(0);
      }
    }
    __syncthreads();
  }

#pragma unroll
  for (int m = 0; m < 2; m++) {
    float lr[4];
#pragma unroll
    for (int r = 0; r < 4; r++) lr[r] = 1.0f / acc_l[m][r];
#pragma unroll
    for (int f = 0; f < 4; f++)
#pragma unroll
      for (int r = 0; r < 4; r++) {
        int q = q0w + m * 16 + l4 * 4 + r;
        yb[(size_t)q * 1024 + f * 16 + l15] = f2bf(o_acc[m][f][r] * lr[r]);
      }
  }
}

// ---------------------------------------------------------------- launch
extern "C" void kernel_launch(void* const* d_in, const int* in_sizes, int n_in,
                              void* d_out, int out_size, void* d_ws, size_t ws_size,
                              hipStream_t stream) {
  const float* x = (const float*)d_in[0];
  const float* w_qkv = (const float*)d_in[1];
  const float* b_qkv = (const float*)d_in[2];
  const float* w_proj = (const float*)d_in[3];
  const float* b_proj = (const float*)d_in[4];
  float* out = (float*)d_out;
  char* ws = (char*)d_ws;

  const int M = 4 * 2048;
  unsigned short* x_bf = (unsigned short*)ws;                        // 16 MB
  unsigned short* wqkv_bf = (unsigned short*)(ws + (22ull << 20));   // 6 MB
  unsigned short* wproj_bf = (unsigned short*)(ws + (28ull << 20));  // 2 MB
  unsigned short* qk_buf = (unsigned short*)(ws + (30ull << 20));    // 32 MB [8192][2048]
  unsigned short* vt = (unsigned short*)(ws + (62ull << 20));        // 16 MB [4096][2048]
  unsigned short* y_bf = x_bf;  // reuse x region after QKV GEMM

  cvt3_kn<<<2048, 256, 0, stream>>>(x, w_qkv, w_proj, x_bf, wqkv_bf, wproj_bf);

  // QKV: 128x192 tiles -> 16 x 64 = 1024 blocks
  gemm_qkv_kn<<<dim3(16, 64), 256, 0, stream>>>(
      x_bf, wqkv_bf, b_qkv, qk_buf, vt, M, 3072, 1024);

  attn_kn<<<dim3(64, 16), 256, 0, stream>>>(qk_buf, vt, y_bf);

  // proj: 128x128 tiles -> 8 x 64 = 512 blocks
  gemm_proj_kn<<<dim3(8, 64), 256, 0, stream>>>(
      y_bf, wproj_bf, b_proj, out, M, 1024, 1024);
}